// Round 1
// baseline (5312.031 us; speedup 1.0000x reference)
//
#include <hip/hip_runtime.h>

// EdgeTransition fused pipeline, fp32 baseline.
//
// Stage A: nproj[N,64] = node_embed[N,128] @ W_init[128,64] + b_init      (workspace)
// Stage B (per 64-edge tile, 256 threads = 4 waves):
//   lane = edge within tile, wave w owns cols [48w,48w+48) of hidden dims
//   phase1: acc[48]  = b1 + h@W1 (cols of wave)     } h read from LDS, 1 b32/lane/k
//           racc[16] = bf + h@Wf (16 final cols)    } weights are wave-uniform -> s_load
//   t1 = relu(acc) -> LDS (same buffer, barriered)
//   phase2: acc[48] = b2 + t1@W2 ; t2 = relu -> LDS
//   phase3: racc += t2@Wf
//   LN(64) via 4-lane shuffle reduction, coalesced float stores.
//
// LDS: single 64x193 f32 buffer (49.4 KB) -> 3 blocks/CU. Stride 193 makes
// the per-k column read bank-conflict-free ((lane+k)%32).

#define LN_EPS 1e-5f

__global__ __launch_bounds__(256) void node_proj_kernel(
    const float* __restrict__ node_embed,
    const float* __restrict__ W_init,   // [128,64]
    const float* __restrict__ b_init,   // [64]
    float* __restrict__ nproj,          // [N,64]
    int n_nodes)
{
    __shared__ float Wl[128 * 64];      // 32 KB
    __shared__ float rowl[4][129];      // padded: write banks (w*129+l)%32 distinct

    const int tid = threadIdx.x;
    // cooperative load of W_init as float4
    {
        const float4* src = (const float4*)W_init;
        float4* dst = (float4*)Wl;
        #pragma unroll
        for (int i = 0; i < 8; ++i) {
            dst[tid + 256 * i] = src[tid + 256 * i];
        }
    }
    const int w = tid >> 6;   // wave 0..3 -> node within group
    const int l = tid & 63;   // lane -> output col

    const int v = blockIdx.x * 4 + w;
    float r0 = 0.f, r1 = 0.f;
    if (v < n_nodes) {
        r0 = node_embed[v * 128 + l];
        r1 = node_embed[v * 128 + 64 + l];
    }
    rowl[w][l] = r0;          // only lanes 0..63 of wave w touch rowl[w][0..63]
    // second half: cols 64..127
    __syncthreads();          // covers Wl + rowl halves? need rowl[64+l] too:
    // NOTE: store both halves before the barrier instead:
    // (restructured below to keep a single barrier)
    if (true) {}
    // -- we must write the upper half before compute; do it now and re-barrier.
    rowl[w][64 + l] = r1;     // distinct region, no race with reads yet
    __syncthreads();

    if (v < n_nodes) {
        float acc = b_init[l];
        #pragma unroll 4
        for (int k = 0; k < 128; ++k) {
            acc = fmaf(rowl[w][k], Wl[k * 64 + l], acc);
        }
        nproj[v * 64 + l] = acc;
    }
}

__global__ __launch_bounds__(256, 3) void edge_mlp_kernel(
    const float* __restrict__ edge_embed,   // [E,64]
    const int*   __restrict__ edge_index,   // [2,E] int32
    const float* __restrict__ nproj,        // [N,64]
    const float* __restrict__ W1,           // [192,192]
    const float* __restrict__ b1,           // [192]
    const float* __restrict__ W2,           // [192,192]
    const float* __restrict__ b2,           // [192]
    const float* __restrict__ Wf,           // [192,64]
    const float* __restrict__ bfin,         // [64]
    const float* __restrict__ gamma,        // [64]
    const float* __restrict__ beta,         // [64]
    float* __restrict__ out,                // [E,64]
    int n_edges)
{
    __shared__ float smem[64 * 193];        // 49408 B; reused h -> t1 -> t2 -> e

    const int tid  = threadIdx.x;
    const int wav  = __builtin_amdgcn_readfirstlane(tid >> 6);  // 0..3, scalar
    const int lane = tid & 63;                                   // edge in tile
    const int e0   = blockIdx.x * 64;

    // ---------------- staging: h rows [64 edges][192] ----------------
    {
        const int e = tid >> 2;   // 0..63
        const int q = tid & 3;    // 0..3 (16-float chunk)
        int eg = e0 + e;
        if (eg >= n_edges) eg = 0;               // safe clamp (reads only)
        const int vi = edge_index[eg];
        const int vj = edge_index[n_edges + eg];
        const float4* s0 = (const float4*)(edge_embed + (size_t)eg * 64 + q * 16);
        const float4* s1 = (const float4*)(nproj + (size_t)vi * 64 + q * 16);
        const float4* s2 = (const float4*)(nproj + (size_t)vj * 64 + q * 16);
        float* d0 = smem + e * 193 + q * 16;
        #pragma unroll
        for (int m = 0; m < 4; ++m) {
            float4 a = s0[m];
            d0[4 * m + 0] = a.x; d0[4 * m + 1] = a.y;
            d0[4 * m + 2] = a.z; d0[4 * m + 3] = a.w;
        }
        float* d1 = d0 + 64;
        #pragma unroll
        for (int m = 0; m < 4; ++m) {
            float4 a = s1[m];
            d1[4 * m + 0] = a.x; d1[4 * m + 1] = a.y;
            d1[4 * m + 2] = a.z; d1[4 * m + 3] = a.w;
        }
        float* d2 = d0 + 128;
        #pragma unroll
        for (int m = 0; m < 4; ++m) {
            float4 a = s2[m];
            d2[4 * m + 0] = a.x; d2[4 * m + 1] = a.y;
            d2[4 * m + 2] = a.z; d2[4 * m + 3] = a.w;
        }
    }
    __syncthreads();

    const float* hrow = smem + lane * 193;

    // ---------------- phase 1: t1 partial + h@Wf ----------------
    float acc[48];
    float racc[16];
    {
        const float* bb = b1 + wav * 48;
        #pragma unroll
        for (int c = 0; c < 48; ++c) acc[c] = bb[c];
        const float* bbf = bfin + wav * 16;
        #pragma unroll
        for (int c = 0; c < 16; ++c) racc[c] = bbf[c];

        const float* w1p = W1 + wav * 48;
        const float* wfp = Wf + wav * 16;
        #pragma unroll 2
        for (int k = 0; k < 192; ++k) {
            const float hv = hrow[k];
            const float* wr = w1p + k * 192;
            #pragma unroll
            for (int c = 0; c < 48; ++c) acc[c] = fmaf(hv, wr[c], acc[c]);
            const float* fr = wfp + k * 64;
            #pragma unroll
            for (int c = 0; c < 16; ++c) racc[c] = fmaf(hv, fr[c], racc[c]);
        }
    }
    __syncthreads();
    {   // write t1 = relu(acc) into smem[lane][wav*48 + c]
        float* trow = smem + lane * 193 + wav * 48;
        #pragma unroll
        for (int c = 0; c < 48; ++c) trow[c] = fmaxf(acc[c], 0.0f);
    }
    __syncthreads();

    // ---------------- phase 2: t2 = relu(t1 @ W2 + b2) ----------------
    {
        const float* bb = b2 + wav * 48;
        #pragma unroll
        for (int c = 0; c < 48; ++c) acc[c] = bb[c];
        const float* w2p = W2 + wav * 48;
        #pragma unroll 2
        for (int k = 0; k < 192; ++k) {
            const float tv = hrow[k];
            const float* wr = w2p + k * 192;
            #pragma unroll
            for (int c = 0; c < 48; ++c) acc[c] = fmaf(tv, wr[c], acc[c]);
        }
    }
    __syncthreads();
    {
        float* trow = smem + lane * 193 + wav * 48;
        #pragma unroll
        for (int c = 0; c < 48; ++c) trow[c] = fmaxf(acc[c], 0.0f);
    }
    __syncthreads();

    // ---------------- phase 3: racc += t2 @ Wf ----------------
    {
        const float* wfp = Wf + wav * 16;
        #pragma unroll 2
        for (int k = 0; k < 192; ++k) {
            const float tv = hrow[k];
            const float* fr = wfp + k * 64;
            #pragma unroll
            for (int c = 0; c < 16; ++c) racc[c] = fmaf(tv, fr[c], racc[c]);
        }
    }
    __syncthreads();
    {   // stash e rows as [64][65] in the same LDS
        float* erow = smem + lane * 65 + wav * 16;
        #pragma unroll
        for (int c = 0; c < 16; ++c) erow[c] = racc[c];
    }
    __syncthreads();

    // ---------------- LayerNorm(64) + store ----------------
    {
        const int e = tid >> 2;   // edge
        const int q = tid & 3;    // 16-col chunk
        const float* er = smem + e * 65 + q * 16;
        float vals[16];
        float s = 0.f, s2 = 0.f;
        #pragma unroll
        for (int i = 0; i < 16; ++i) {
            float v = er[i];
            vals[i] = v;
            s += v;
            s2 += v * v;
        }
        s  += __shfl_xor(s, 1);   s  += __shfl_xor(s, 2);
        s2 += __shfl_xor(s2, 1);  s2 += __shfl_xor(s2, 2);
        const float mu   = s * (1.0f / 64.0f);
        const float var  = s2 * (1.0f / 64.0f) - mu * mu;
        const float rstd = rsqrtf(var + LN_EPS);
        const int eg = e0 + e;
        if (eg < n_edges) {
            float* op = out + (size_t)eg * 64 + q * 16;
            #pragma unroll
            for (int i = 0; i < 16; ++i) {
                op[i] = (vals[i] - mu) * rstd * gamma[q * 16 + i] + beta[q * 16 + i];
            }
        }
    }
}

extern "C" void kernel_launch(void* const* d_in, const int* in_sizes, int n_in,
                              void* d_out, int out_size, void* d_ws, size_t ws_size,
                              hipStream_t stream) {
    const float* node_embed = (const float*)d_in[0];
    const float* edge_embed = (const float*)d_in[1];
    const int*   edge_index = (const int*)d_in[2];
    const float* W_init     = (const float*)d_in[3];
    const float* b_init     = (const float*)d_in[4];
    const float* W1         = (const float*)d_in[5];
    const float* b1         = (const float*)d_in[6];
    const float* W2         = (const float*)d_in[7];
    const float* b2         = (const float*)d_in[8];
    const float* Wf         = (const float*)d_in[9];
    const float* bfin       = (const float*)d_in[10];
    const float* gamma      = (const float*)d_in[11];
    const float* beta       = (const float*)d_in[12];
    float* out = (float*)d_out;

    const int n_nodes = in_sizes[0] / 128;
    const int n_edges = in_sizes[1] / 64;

    float* nproj = (float*)d_ws;   // n_nodes*64 floats = 25.6 MB

    node_proj_kernel<<<(n_nodes + 3) / 4, 256, 0, stream>>>(
        node_embed, W_init, b_init, nproj, n_nodes);

    edge_mlp_kernel<<<(n_edges + 63) / 64, 256, 0, stream>>>(
        edge_embed, edge_index, nproj,
        W1, b1, W2, b2, Wf, bfin, gamma, beta, out, n_edges);
}

// Round 2
// 671.239 us; speedup vs baseline: 7.9138x; 7.9138x over previous
//
#include <hip/hip_runtime.h>

// EdgeTransition fused pipeline, bf16-MFMA version.
//
// d_ws layout:
//   [0)            nproj bf16 [N_NODES, 64]              12,800,000 B
//   [+12800000)    W1p  packed bf16 frags (12 nt,6 ks)       73,728 B
//   [+12873728)    W2p  packed                               73,728 B
//   [+12947456)    Wfp  packed (4 nt, 6 ks)                  24,576 B
//   [+12972032)    Wip  packed (4 nt, 4 ks)                  16,384 B
//
// Fragment conventions (mfma_f32_16x16x32_bf16, guide §3 m89/m120-verified):
//   A: lane holds A[m=lane&15][k=quad*8+j], j=0..7   (quad = lane>>4)
//   B: lane holds B[k=quad*8+j][n=lane&15]
//   C/D: col = lane&15, row = quad*4 + reg

typedef __bf16 bf16x8 __attribute__((ext_vector_type(8)));
typedef float  f32x4  __attribute__((ext_vector_type(4)));

#define LN_EPS 1e-5f

// ---------------- weight packing ----------------
__global__ __launch_bounds__(256) void pack_weights_kernel(
    const float* __restrict__ W, int KS, int NT, int N,
    __bf16* __restrict__ dst, int total)
{
    const int t = blockIdx.x * 256 + threadIdx.x;
    if (t >= total) return;
    const int lane = t & 63;
    const int ks   = (t >> 6) % KS;
    const int nt   = t / (KS * 64);
    const int n  = nt * 16 + (lane & 15);
    const int k0 = ks * 32 + (lane >> 4) * 8;
    bf16x8 v;
    #pragma unroll
    for (int j = 0; j < 8; ++j) v[j] = (__bf16)W[(k0 + j) * N + n];
    *(bf16x8*)(dst + (size_t)t * 8) = v;
}

// ---------------- node projection: nproj = node @ W_init + b ----------------
__global__ __launch_bounds__(256) void node_proj_mfma(
    const float* __restrict__ node_embed,   // [N,128]
    const __bf16* __restrict__ Wip,         // packed [4 nt][4 ks][64][8]
    const float* __restrict__ b_init,       // [64]
    __bf16* __restrict__ nproj,             // [N,64] bf16
    int n_nodes)
{
    __shared__ __bf16 nl[64 * 136];         // 17.4 KB, stride 136 (pad)
    const int tid = threadIdx.x;
    const int v0  = blockIdx.x * 64;

    {   // stage 64 node rows, fp32 -> bf16
        const int e = tid >> 2, q = tid & 3;
        const int v = v0 + e;
        if (v < n_nodes) {
            const float4* src = (const float4*)(node_embed + (size_t)v * 128 + q * 32);
            #pragma unroll
            for (int m = 0; m < 4; ++m) {
                float4 a = src[2 * m], b = src[2 * m + 1];
                bf16x8 w;
                w[0]=(__bf16)a.x; w[1]=(__bf16)a.y; w[2]=(__bf16)a.z; w[3]=(__bf16)a.w;
                w[4]=(__bf16)b.x; w[5]=(__bf16)b.y; w[6]=(__bf16)b.z; w[7]=(__bf16)b.w;
                *(bf16x8*)(nl + e * 136 + q * 32 + m * 8) = w;
            }
        } else {
            bf16x8 z = {};
            #pragma unroll
            for (int m = 0; m < 4; ++m)
                *(bf16x8*)(nl + e * 136 + q * 32 + m * 8) = z;
        }
    }
    __syncthreads();

    const int wav = tid >> 6, lane = tid & 63;
    const int l15 = lane & 15, quad = lane >> 4;

    f32x4 acc[4] = {};
    #pragma unroll
    for (int ks = 0; ks < 4; ++ks) {
        bf16x8 a = *(const bf16x8*)(nl + (16 * wav + l15) * 136 + ks * 32 + quad * 8);
        #pragma unroll
        for (int nt = 0; nt < 4; ++nt) {
            bf16x8 b = *(const bf16x8*)(Wip + ((size_t)(nt * 4 + ks) * 64 + lane) * 8);
            acc[nt] = __builtin_amdgcn_mfma_f32_16x16x32_bf16(a, b, acc[nt], 0, 0, 0);
        }
    }
    #pragma unroll
    for (int nt = 0; nt < 4; ++nt) {
        const float bb = b_init[nt * 16 + l15];
        #pragma unroll
        for (int r = 0; r < 4; ++r) {
            const int row = v0 + 16 * wav + quad * 4 + r;
            if (row < n_nodes)
                nproj[(size_t)row * 64 + nt * 16 + l15] = (__bf16)(acc[nt][r] + bb);
        }
    }
}

// ---------------- edge MLP ----------------
__global__ __launch_bounds__(256, 3) void edge_mlp_mfma(
    const float*  __restrict__ edge_embed,  // [E,64] fp32
    const int*    __restrict__ edge_index,  // [2,E]
    const __bf16* __restrict__ npr,         // [N,64] bf16
    const __bf16* __restrict__ W1p,         // [12 nt][6 ks][64][8]
    const float*  __restrict__ b1,
    const __bf16* __restrict__ W2p,
    const float*  __restrict__ b2,
    const __bf16* __restrict__ Wfp,         // [4 nt][6 ks][64][8]
    const float*  __restrict__ bfin,
    const float*  __restrict__ gamma,
    const float*  __restrict__ beta,
    float* __restrict__ out,                // [E,64]
    int n_edges)
{
    __shared__ __bf16 hl[64 * 200];         // h, 25.6 KB (stride 200)
    __shared__ __bf16 tl[64 * 200];         // t1 then t2
    float* e_lds = reinterpret_cast<float*>(hl);   // reused after h dead: [64][68] fp32

    const int tid  = threadIdx.x;
    const int wav  = tid >> 6;
    const int lane = tid & 63;
    const int l15  = lane & 15, quad = lane >> 4;
    const int e0   = blockIdx.x * 64;

    // ---- staging: h[64][192] bf16 = [edge_embed | nproj[vi] | nproj[vj]] ----
    {
        const int e = tid >> 2, q = tid & 3;
        int eg = e0 + e;
        if (eg >= n_edges) eg = n_edges - 1;
        const int vi = edge_index[eg];
        const int vj = edge_index[n_edges + eg];
        // edge_embed 16 floats -> bf16
        const float4* s0 = (const float4*)(edge_embed + (size_t)eg * 64 + q * 16);
        #pragma unroll
        for (int m = 0; m < 2; ++m) {
            float4 a = s0[2 * m], b = s0[2 * m + 1];
            bf16x8 w;
            w[0]=(__bf16)a.x; w[1]=(__bf16)a.y; w[2]=(__bf16)a.z; w[3]=(__bf16)a.w;
            w[4]=(__bf16)b.x; w[5]=(__bf16)b.y; w[6]=(__bf16)b.z; w[7]=(__bf16)b.w;
            *(bf16x8*)(hl + e * 200 + q * 16 + m * 8) = w;
        }
        // nproj rows already bf16: raw 16B copies
        const int4* s1 = (const int4*)(npr + (size_t)vi * 64 + q * 16);
        const int4* s2 = (const int4*)(npr + (size_t)vj * 64 + q * 16);
        ((int4*)(hl + e * 200 + 64  + q * 16))[0] = s1[0];
        ((int4*)(hl + e * 200 + 64  + q * 16))[1] = s1[1];
        ((int4*)(hl + e * 200 + 128 + q * 16))[0] = s2[0];
        ((int4*)(hl + e * 200 + 128 + q * 16))[1] = s2[1];
    }
    __syncthreads();

    // ---- phase 1: acc = h@W1 (cols 48w..48w+48), racc = h@Wf (cols 16w..16w+16) ----
    f32x4 acc[3][4] = {};
    f32x4 racc[4]   = {};
    #pragma unroll 2
    for (int ks = 0; ks < 6; ++ks) {
        bf16x8 amt[4];
        #pragma unroll
        for (int mt = 0; mt < 4; ++mt)
            amt[mt] = *(const bf16x8*)(hl + (16 * mt + l15) * 200 + ks * 32 + quad * 8);
        #pragma unroll
        for (int nt = 0; nt < 3; ++nt) {
            bf16x8 b = *(const bf16x8*)(W1p + ((size_t)((3 * wav + nt) * 6 + ks) * 64 + lane) * 8);
            #pragma unroll
            for (int mt = 0; mt < 4; ++mt)
                acc[nt][mt] = __builtin_amdgcn_mfma_f32_16x16x32_bf16(amt[mt], b, acc[nt][mt], 0, 0, 0);
        }
        bf16x8 bw = *(const bf16x8*)(Wfp + ((size_t)(wav * 6 + ks) * 64 + lane) * 8);
        #pragma unroll
        for (int mt = 0; mt < 4; ++mt)
            racc[mt] = __builtin_amdgcn_mfma_f32_16x16x32_bf16(amt[mt], bw, racc[mt], 0, 0, 0);
    }
    // t1 = relu(acc + b1) -> tl
    #pragma unroll
    for (int nt = 0; nt < 3; ++nt) {
        const float bb = b1[48 * wav + nt * 16 + l15];
        #pragma unroll
        for (int mt = 0; mt < 4; ++mt)
            #pragma unroll
            for (int r = 0; r < 4; ++r)
                tl[(16 * mt + quad * 4 + r) * 200 + 48 * wav + nt * 16 + l15] =
                    (__bf16)fmaxf(acc[nt][mt][r] + bb, 0.0f);
    }
    __syncthreads();

    // ---- phase 2: acc = t1@W2 ----
    #pragma unroll
    for (int nt = 0; nt < 3; ++nt)
        #pragma unroll
        for (int mt = 0; mt < 4; ++mt)
            acc[nt][mt] = (f32x4){0.f, 0.f, 0.f, 0.f};
    #pragma unroll 2
    for (int ks = 0; ks < 6; ++ks) {
        bf16x8 amt[4];
        #pragma unroll
        for (int mt = 0; mt < 4; ++mt)
            amt[mt] = *(const bf16x8*)(tl + (16 * mt + l15) * 200 + ks * 32 + quad * 8);
        #pragma unroll
        for (int nt = 0; nt < 3; ++nt) {
            bf16x8 b = *(const bf16x8*)(W2p + ((size_t)((3 * wav + nt) * 6 + ks) * 64 + lane) * 8);
            #pragma unroll
            for (int mt = 0; mt < 4; ++mt)
                acc[nt][mt] = __builtin_amdgcn_mfma_f32_16x16x32_bf16(amt[mt], b, acc[nt][mt], 0, 0, 0);
        }
    }
    __syncthreads();   // all reads of t1 done before overwrite
    // t2 = relu(acc + b2) -> tl
    #pragma unroll
    for (int nt = 0; nt < 3; ++nt) {
        const float bb = b2[48 * wav + nt * 16 + l15];
        #pragma unroll
        for (int mt = 0; mt < 4; ++mt)
            #pragma unroll
            for (int r = 0; r < 4; ++r)
                tl[(16 * mt + quad * 4 + r) * 200 + 48 * wav + nt * 16 + l15] =
                    (__bf16)fmaxf(acc[nt][mt][r] + bb, 0.0f);
    }
    __syncthreads();

    // ---- phase 3: racc += t2@Wf ----
    #pragma unroll 2
    for (int ks = 0; ks < 6; ++ks) {
        bf16x8 bw = *(const bf16x8*)(Wfp + ((size_t)(wav * 6 + ks) * 64 + lane) * 8);
        #pragma unroll
        for (int mt = 0; mt < 4; ++mt) {
            bf16x8 a = *(const bf16x8*)(tl + (16 * mt + l15) * 200 + ks * 32 + quad * 8);
            racc[mt] = __builtin_amdgcn_mfma_f32_16x16x32_bf16(a, bw, racc[mt], 0, 0, 0);
        }
    }
    // E rows -> e_lds fp32 [64][68]  (hl region; h is dead)
    {
        const float bb = bfin[16 * wav + l15];
        #pragma unroll
        for (int mt = 0; mt < 4; ++mt)
            #pragma unroll
            for (int r = 0; r < 4; ++r)
                e_lds[(16 * mt + quad * 4 + r) * 68 + 16 * wav + l15] = racc[mt][r] + bb;
    }
    __syncthreads();

    // ---- LayerNorm(64) + store ----
    {
        const int e = tid >> 2, q = tid & 3;
        const float* er = e_lds + e * 68 + q * 16;
        float vals[16];
        float s = 0.f, s2 = 0.f;
        #pragma unroll
        for (int i = 0; i < 16; ++i) {
            float v = er[i];
            vals[i] = v;
            s += v; s2 += v * v;
        }
        s  += __shfl_xor(s, 1);   s  += __shfl_xor(s, 2);
        s2 += __shfl_xor(s2, 1);  s2 += __shfl_xor(s2, 2);
        const float mu   = s * (1.0f / 64.0f);
        const float var  = s2 * (1.0f / 64.0f) - mu * mu;
        const float rstd = rsqrtf(var + LN_EPS);
        const int eg = e0 + e;
        if (eg < n_edges) {
            float* op = out + (size_t)eg * 64 + q * 16;
            #pragma unroll
            for (int i = 0; i < 16; ++i)
                op[i] = (vals[i] - mu) * rstd * gamma[q * 16 + i] + beta[q * 16 + i];
        }
    }
}

extern "C" void kernel_launch(void* const* d_in, const int* in_sizes, int n_in,
                              void* d_out, int out_size, void* d_ws, size_t ws_size,
                              hipStream_t stream) {
    const float* node_embed = (const float*)d_in[0];
    const float* edge_embed = (const float*)d_in[1];
    const int*   edge_index = (const int*)d_in[2];
    const float* W_init     = (const float*)d_in[3];
    const float* b_init     = (const float*)d_in[4];
    const float* W1         = (const float*)d_in[5];
    const float* b1         = (const float*)d_in[6];
    const float* W2         = (const float*)d_in[7];
    const float* b2         = (const float*)d_in[8];
    const float* Wf         = (const float*)d_in[9];
    const float* bfin       = (const float*)d_in[10];
    const float* gamma      = (const float*)d_in[11];
    const float* beta       = (const float*)d_in[12];
    float* out = (float*)d_out;

    const int n_nodes = in_sizes[0] / 128;
    const int n_edges = in_sizes[1] / 64;

    char* ws = (char*)d_ws;
    __bf16* nproj = (__bf16*)ws;
    __bf16* W1p   = (__bf16*)(ws + 12800000);
    __bf16* W2p   = (__bf16*)(ws + 12873728);
    __bf16* Wfp   = (__bf16*)(ws + 12947456);
    __bf16* Wip   = (__bf16*)(ws + 12972032);

    // pack weights (bf16 fragment layout)
    pack_weights_kernel<<<18, 256, 0, stream>>>(W1, 6, 12, 192, W1p, 12 * 6 * 64);
    pack_weights_kernel<<<18, 256, 0, stream>>>(W2, 6, 12, 192, W2p, 12 * 6 * 64);
    pack_weights_kernel<<< 6, 256, 0, stream>>>(Wf, 6,  4,  64, Wfp,  4 * 6 * 64);
    pack_weights_kernel<<< 4, 256, 0, stream>>>(W_init, 4, 4, 64, Wip, 4 * 4 * 64);

    node_proj_mfma<<<(n_nodes + 63) / 64, 256, 0, stream>>>(
        node_embed, Wip, b_init, nproj, n_nodes);

    edge_mlp_mfma<<<(n_edges + 63) / 64, 256, 0, stream>>>(
        edge_embed, edge_index, nproj,
        W1p, b1, W2p, b2, Wfp, bfin, gamma, beta, out, n_edges);
}